// Round 4
// baseline (241.001 us; speedup 1.0000x reference)
//
#include <hip/hip_runtime.h>
#include <hip/hip_bf16.h>

using bf16x8 = __attribute__((ext_vector_type(8))) __bf16;
using f32x4  = __attribute__((ext_vector_type(4))) float;
typedef unsigned short ushort_t;

#define M_DIM 16384
#define K_DIM 4096
#define N_DIM 1024

// Inline-asm barrier, opaque to SIInsertWaitcnts: the builtin S_BARRIER makes
// the waitcnt pass conservatively drain outstanding LDS-DMA (global_load_lds)
// each phase, defeating the counted-vmcnt pipeline (R2/R3 evidence: 8-phase ==
// 2-phase at 31% MfmaUtil). sched_barrier(0) on both sides pins scheduling so
// no memory op crosses the opaque asm (rule #18).
#define BARR() do { __builtin_amdgcn_sched_barrier(0); \
                    asm volatile("s_barrier");          \
                    __builtin_amdgcn_sched_barrier(0); } while (0)

__device__ __forceinline__ unsigned short f2bf(float f) {
  __hip_bfloat16 h = __float2bfloat16(f);  // RNE
  return *reinterpret_cast<unsigned short*>(&h);
}

__device__ __forceinline__ float snap(float a) {
  float q = 0.0f;
  q += (a > 0.25f) ? 0.5f : 0.0f;
  q += (a > 0.75f) ? 0.5f : 0.0f;
  q += (a > 1.25f) ? 0.5f : 0.0f;
  q += (a > 1.75f) ? 0.5f : 0.0f;
  q += (a > 2.5f)  ? 1.0f : 0.0f;
  q += (a > 3.5f)  ? 1.0f : 0.0f;
  q += (a > 5.0f)  ? 2.0f : 0.0f;
  return q;
}

__device__ __forceinline__ unsigned short qdq(float xv, float rs, float scale) {
  float xs = xv * rs;
  float q  = copysignf(snap(fabsf(xs)), xs);
  return f2bf(q * scale);
}

// One 16-lane cluster per 128-elem group; 4 groups per wave, 16 per block.
__global__ __launch_bounds__(256) void quant_kernel(const float* __restrict__ x,
                                                    unsigned short* __restrict__ dq) {
  const int wid = (blockIdx.x << 2) + (threadIdx.x >> 6);
  const int l   = threadIdx.x & 63;
  const int sub = l >> 4, t = l & 15;
  const size_t base = ((size_t)wid * 4 + sub) * 128;
  const float4* px = reinterpret_cast<const float4*>(x + base);
  float4 v0 = px[t];
  float4 v1 = px[16 + t];
  float amax = fmaxf(fmaxf(fmaxf(fabsf(v0.x), fabsf(v0.y)), fmaxf(fabsf(v0.z), fabsf(v0.w))),
                     fmaxf(fmaxf(fabsf(v1.x), fabsf(v1.y)), fmaxf(fabsf(v1.z), fabsf(v1.w))));
  #pragma unroll
  for (int m = 1; m < 16; m <<= 1) amax = fmaxf(amax, __shfl_xor(amax, m, 64));
  float scale = amax / 6.0f;
  if (scale == 0.0f) scale = 1.0f;
  const float rs = 1.0f / scale;
  ushort4 o0, o1;
  o0.x = qdq(v0.x, rs, scale); o0.y = qdq(v0.y, rs, scale);
  o0.z = qdq(v0.z, rs, scale); o0.w = qdq(v0.w, rs, scale);
  o1.x = qdq(v1.x, rs, scale); o1.y = qdq(v1.y, rs, scale);
  o1.z = qdq(v1.z, rs, scale); o1.w = qdq(v1.w, rs, scale);
  reinterpret_cast<ushort4*>(dq + base)[t]      = o0;
  reinterpret_cast<ushort4*>(dq + base)[16 + t] = o1;
}

__global__ __launch_bounds__(256) void wconv_kernel(const float* __restrict__ w,
                                                    unsigned short* __restrict__ o) {
  const int n4 = (N_DIM * K_DIM) / 4;
  for (int i = blockIdx.x * 256 + threadIdx.x; i < n4; i += gridDim.x * 256) {
    float4 v = reinterpret_cast<const float4*>(w)[i];
    ushort4 u;
    u.x = f2bf(v.x); u.y = f2bf(v.y); u.z = f2bf(v.z); u.w = f2bf(v.w);
    reinterpret_cast<ushort4*>(o)[i] = u;
  }
}

__device__ __forceinline__ bf16x8 lds_ld(const ushort_t* p) {
  return *reinterpret_cast<const bf16x8*>(p);
}

// Stage one 16KB half-tile (128 rows x 64 cols bf16) block-wide: 2 x 16B per thread.
// LDS dest linear (wave-uniform base + lane*16); swizzle pre-applied on the global
// source address (T21: both-sides-or-neither).
__device__ __forceinline__ void stg(const ushort_t* g0, const ushort_t* g1,
                                    ushort_t* slot, int wid) {
  __builtin_amdgcn_global_load_lds((const __attribute__((address_space(1))) void*)g0,
      (__attribute__((address_space(3))) void*)(slot + wid * 512), 16, 0, 0);
  __builtin_amdgcn_global_load_lds((const __attribute__((address_space(1))) void*)g1,
      (__attribute__((address_space(3))) void*)(slot + 4096 + wid * 512), 16, 0, 0);
}

// One K-tile (BK=64): 4 phases, each {ds_reads -> 1 half-tile stage -> barrier ->
// 16 MFMA (setprio-wrapped) -> barrier}; counted vmcnt(4) only at phase 4.
template<bool S12, bool S34, int VM>
__device__ __forceinline__ void tile_iter(
    int t, ushort_t* sA, ushort_t* sB, int wid, int wm, int wn,
    const int (&roA)[8], const int (&roB)[4], int swz0, int swz1,
    const ushort_t* pa0, const ushort_t* pa1,
    const ushort_t* pb0, const ushort_t* pb1,
    f32x4 (&acc)[8][4]) {
  const int par = t & 1;
  const ushort_t* slA = sA + (wm * 2 + par) * 8192;
  const ushort_t* slB = sB + ((wn >> 1) * 2 + par) * 8192;
  bf16x8 a0[4], a1[4], b0[4], b1[4];

  // ---- phase 1: read A(m0-3,kk0/1) + B(n0-1); stage B1(t+1); MFMA (m0-3 x n0-1)
  #pragma unroll
  for (int i = 0; i < 4; ++i) {
    a0[i] = lds_ld(slA + roA[i] + swz0);
    a1[i] = lds_ld(slA + roA[i] + swz1);
  }
  #pragma unroll
  for (int n = 0; n < 2; ++n) {
    b0[n] = lds_ld(slB + roB[n] + swz0);
    b1[n] = lds_ld(slB + roB[n] + swz1);
  }
  if constexpr (S12)
    stg(pb0 + (size_t)128 * K_DIM + (size_t)(t + 1) * 64,
        pb1 + (size_t)128 * K_DIM + (size_t)(t + 1) * 64,
        sB + (2 + ((t + 1) & 1)) * 8192, wid);
  BARR();
  __builtin_amdgcn_s_setprio(1);
  #pragma unroll
  for (int i = 0; i < 4; ++i)
    #pragma unroll
    for (int n = 0; n < 2; ++n) {
      acc[i][n] = __builtin_amdgcn_mfma_f32_16x16x32_bf16(a0[i], b0[n], acc[i][n], 0, 0, 0);
      acc[i][n] = __builtin_amdgcn_mfma_f32_16x16x32_bf16(a1[i], b1[n], acc[i][n], 0, 0, 0);
    }
  __builtin_amdgcn_s_setprio(0);
  BARR();

  // ---- phase 2: read B(n2-3); stage A1(t+1); MFMA (m0-3 x n2-3)
  #pragma unroll
  for (int n = 2; n < 4; ++n) {
    b0[n] = lds_ld(slB + roB[n] + swz0);
    b1[n] = lds_ld(slB + roB[n] + swz1);
  }
  if constexpr (S12)
    stg(pa0 + (size_t)128 * K_DIM + (size_t)(t + 1) * 64,
        pa1 + (size_t)128 * K_DIM + (size_t)(t + 1) * 64,
        sA + (2 + ((t + 1) & 1)) * 8192, wid);
  BARR();
  __builtin_amdgcn_s_setprio(1);
  #pragma unroll
  for (int i = 0; i < 4; ++i)
    #pragma unroll
    for (int n = 2; n < 4; ++n) {
      acc[i][n] = __builtin_amdgcn_mfma_f32_16x16x32_bf16(a0[i], b0[n], acc[i][n], 0, 0, 0);
      acc[i][n] = __builtin_amdgcn_mfma_f32_16x16x32_bf16(a1[i], b1[n], acc[i][n], 0, 0, 0);
    }
  __builtin_amdgcn_s_setprio(0);
  BARR();

  // ---- phase 3: read A(m4-7); stage B0(t+2); MFMA (m4-7 x n2-3)
  #pragma unroll
  for (int i = 0; i < 4; ++i) {
    a0[i] = lds_ld(slA + roA[4 + i] + swz0);
    a1[i] = lds_ld(slA + roA[4 + i] + swz1);
  }
  if constexpr (S34)
    stg(pb0 + (size_t)(t + 2) * 64, pb1 + (size_t)(t + 2) * 64, sB + par * 8192, wid);
  BARR();
  __builtin_amdgcn_s_setprio(1);
  #pragma unroll
  for (int i = 0; i < 4; ++i)
    #pragma unroll
    for (int n = 2; n < 4; ++n) {
      acc[4 + i][n] = __builtin_amdgcn_mfma_f32_16x16x32_bf16(a0[i], b0[n], acc[4 + i][n], 0, 0, 0);
      acc[4 + i][n] = __builtin_amdgcn_mfma_f32_16x16x32_bf16(a1[i], b1[n], acc[4 + i][n], 0, 0, 0);
    }
  __builtin_amdgcn_s_setprio(0);
  BARR();

  // ---- phase 4: stage A0(t+2); MFMA (m4-7 x n0-1); counted vmcnt; barrier
  if constexpr (S34)
    stg(pa0 + (size_t)(t + 2) * 64, pa1 + (size_t)(t + 2) * 64, sA + par * 8192, wid);
  BARR();
  __builtin_amdgcn_s_setprio(1);
  #pragma unroll
  for (int i = 0; i < 4; ++i)
    #pragma unroll
    for (int n = 0; n < 2; ++n) {
      acc[4 + i][n] = __builtin_amdgcn_mfma_f32_16x16x32_bf16(a0[i], b0[n], acc[4 + i][n], 0, 0, 0);
      acc[4 + i][n] = __builtin_amdgcn_mfma_f32_16x16x32_bf16(a1[i], b1[n], acc[4 + i][n], 0, 0, 0);
    }
  __builtin_amdgcn_s_setprio(0);
  if constexpr (VM == 4) {
    asm volatile("s_waitcnt vmcnt(4)");
    __builtin_amdgcn_sched_barrier(0);   // rule #18: pin later ds_reads below the wait
  } else if constexpr (VM == 0) {
    asm volatile("s_waitcnt vmcnt(0)");
    __builtin_amdgcn_sched_barrier(0);
  }
  BARR();
}

// 256x256 tile, BK=64, 8 waves (2M x 4N), 8-phase/2-half-tile-deep schedule,
// XOR swizzle, counted vmcnt. A = deq [M,K], B = W [N,K] (both row-major bf16).
__global__ __launch_bounds__(512, 2) void gemm256(const ushort_t* __restrict__ A,
                                                  const ushort_t* __restrict__ B,
                                                  const float* __restrict__ bias,
                                                  float* __restrict__ C) {
  __shared__ ushort_t sA[4 * 8192];   // A half-tile slots: [half*2 + parity]
  __shared__ ushort_t sB[4 * 8192];
  const int tid  = threadIdx.x;
  const int wid  = tid >> 6, lane = tid & 63;
  const int r    = lane & 15, h = lane >> 4;
  const int wm   = wid >> 2, wn = wid & 3;
  const int bn   = blockIdx.x, bm = blockIdx.y;

  // ds_read swizzle constants: col16-slice = (kk*4+h) ^ (row&7); row&7 == r&7.
  const int x7   = r & 7;
  const int swz0 = ((h) ^ x7) << 3;         // ushort offset, kk=0
  const int swz1 = ((4 | h) ^ x7) << 3;     // kk=1
  int roA[8], roB[4];
  #pragma unroll
  for (int m = 0; m < 8; ++m) roA[m] = (m * 16 + r) * 64;
  #pragma unroll
  for (int n = 0; n < 4; ++n) roB[n] = ((wn & 1) * 64 + n * 16 + r) * 64;

  // staging source constants: LDS row = tid>>3, 16B-slice q = tid&7,
  // global slice s = q ^ (row&7)  (inverse of the read-side XOR).
  const int srow0 = tid >> 3;
  const int cst   = ((tid & 7) ^ (srow0 & 7)) << 3;   // ushort col offset
  const ushort_t* pa0 = A + (size_t)(bm * 256 + srow0) * K_DIM + cst;
  const ushort_t* pa1 = A + (size_t)(bm * 256 + 64 + srow0) * K_DIM + cst;
  const ushort_t* pb0 = B + (size_t)(bn * 256 + srow0) * K_DIM + cst;
  const ushort_t* pb1 = B + (size_t)(bn * 256 + 64 + srow0) * K_DIM + cst;

  f32x4 acc[8][4];
  #pragma unroll
  for (int m = 0; m < 8; ++m)
    #pragma unroll
    for (int n = 0; n < 4; ++n) acc[m][n] = (f32x4){0.f, 0.f, 0.f, 0.f};

  // Prologue: B0(0) A0(0) B1(0) A1(0) B0(1) A0(1); keep last 2 half-tiles in flight.
  stg(pb0, pb1, sB + 0 * 8192, wid);
  stg(pa0, pa1, sA + 0 * 8192, wid);
  stg(pb0 + (size_t)128 * K_DIM, pb1 + (size_t)128 * K_DIM, sB + 2 * 8192, wid);
  stg(pa0 + (size_t)128 * K_DIM, pa1 + (size_t)128 * K_DIM, sA + 2 * 8192, wid);
  stg(pb0 + 64, pb1 + 64, sB + 1 * 8192, wid);
  stg(pa0 + 64, pa1 + 64, sA + 1 * 8192, wid);
  asm volatile("s_waitcnt vmcnt(4)");
  __builtin_amdgcn_sched_barrier(0);
  BARR();

  for (int t = 0; t < (K_DIM / 64) - 2; ++t)
    tile_iter<true, true, 4>(t, sA, sB, wid, wm, wn, roA, roB, swz0, swz1,
                             pa0, pa1, pb0, pb1, acc);
  tile_iter<true, false, 0>((K_DIM / 64) - 2, sA, sB, wid, wm, wn, roA, roB,
                            swz0, swz1, pa0, pa1, pb0, pb1, acc);
  tile_iter<false, false, -1>((K_DIM / 64) - 1, sA, sB, wid, wm, wn, roA, roB,
                              swz0, swz1, pa0, pa1, pb0, pb1, acc);

  // Epilogue: C/D layout col=lane&15, row=(lane>>4)*4+reg  [m89/m91]
  const int orow = bm * 256 + wm * 128;
  const int ocol = bn * 256 + wn * 64;
  #pragma unroll
  for (int n = 0; n < 4; ++n) {
    const int col = ocol + n * 16 + r;
    const float bv = bias[col];
    #pragma unroll
    for (int m = 0; m < 8; ++m) {
      const int rb = orow + m * 16 + h * 4;
      #pragma unroll
      for (int j = 0; j < 4; ++j)
        C[(size_t)(rb + j) * N_DIM + col] = acc[m][n][j] + bv;
    }
  }
}

// Emergency fallback if ws is too small: fused fp32, slow but correct.
__global__ __launch_bounds__(256) void fused_naive(const float* __restrict__ x,
                                                   const float* __restrict__ w,
                                                   const float* __restrict__ bias,
                                                   float* __restrict__ out) {
  __shared__ float xq[K_DIM];
  const int row = blockIdx.x;
  const float* xr = x + (size_t)row * K_DIM;
  const int t = threadIdx.x;
  const int g = t >> 3, s = t & 7;
  float vals[16];
  float amax = 0.f;
  #pragma unroll
  for (int i = 0; i < 16; ++i) {
    vals[i] = xr[g * 128 + s * 16 + i];
    amax = fmaxf(amax, fabsf(vals[i]));
  }
  #pragma unroll
  for (int m = 1; m < 8; m <<= 1) amax = fmaxf(amax, __shfl_xor(amax, m, 64));
  float scale = amax / 6.0f;
  if (scale == 0.f) scale = 1.f;
  const float rs = 1.0f / scale;
  #pragma unroll
  for (int i = 0; i < 16; ++i) {
    float xs = vals[i] * rs;
    xq[g * 128 + s * 16 + i] = copysignf(snap(fabsf(xs)), xs) * scale;
  }
  __syncthreads();
  #pragma unroll
  for (int i = 0; i < 4; ++i) {
    const int o = i * 256 + t;
    const float* wrow = w + (size_t)o * K_DIM;
    float acc = 0.f;
    for (int k = 0; k < K_DIM; k += 4) {
      float4 wv = *reinterpret_cast<const float4*>(wrow + k);
      acc += xq[k] * wv.x + xq[k + 1] * wv.y + xq[k + 2] * wv.z + xq[k + 3] * wv.w;
    }
    out[(size_t)row * N_DIM + o] = acc + bias[o];
  }
}

extern "C" void kernel_launch(void* const* d_in, const int* in_sizes, int n_in,
                              void* d_out, int out_size, void* d_ws, size_t ws_size,
                              hipStream_t stream) {
  const float* x    = (const float*)d_in[0];
  const float* wgt  = (const float*)d_in[1];
  const float* bias = (const float*)d_in[2];
  float* out = (float*)d_out;

  const size_t deq_bytes = (size_t)M_DIM * K_DIM * 2;
  const size_t wb_bytes  = (size_t)N_DIM * K_DIM * 2;
  if (ws_size >= deq_bytes + wb_bytes) {
    ushort_t* deq = (ushort_t*)d_ws;
    ushort_t* wb  = (ushort_t*)((char*)d_ws + deq_bytes);
    quant_kernel<<<(M_DIM * (K_DIM / 128)) / 16, 256, 0, stream>>>(x, deq);
    wconv_kernel<<<1024, 256, 0, stream>>>(wgt, wb);
    gemm256<<<dim3(N_DIM / 256, M_DIM / 256), 512, 0, stream>>>(deq, wb, bias, out);
  } else {
    fused_naive<<<M_DIM, 256, 0, stream>>>(x, wgt, bias, out);
  }
}

// Round 5
// 217.338 us; speedup vs baseline: 1.1089x; 1.1089x over previous
//
#include <hip/hip_runtime.h>
#include <hip/hip_bf16.h>

using bf16x8 = __attribute__((ext_vector_type(8))) __bf16;
using f32x4  = __attribute__((ext_vector_type(4))) float;
typedef unsigned short ushort_t;

#define M_DIM 16384
#define K_DIM 4096
#define N_DIM 1024

#define BARR() __builtin_amdgcn_s_barrier()

__device__ __forceinline__ unsigned short f2bf(float f) {
  __hip_bfloat16 h = __float2bfloat16(f);  // RNE
  return *reinterpret_cast<unsigned short*>(&h);
}

__device__ __forceinline__ float snap(float a) {
  float q = 0.0f;
  q += (a > 0.25f) ? 0.5f : 0.0f;
  q += (a > 0.75f) ? 0.5f : 0.0f;
  q += (a > 1.25f) ? 0.5f : 0.0f;
  q += (a > 1.75f) ? 0.5f : 0.0f;
  q += (a > 2.5f)  ? 1.0f : 0.0f;
  q += (a > 3.5f)  ? 1.0f : 0.0f;
  q += (a > 5.0f)  ? 2.0f : 0.0f;
  return q;
}

__device__ __forceinline__ unsigned short qdq(float xv, float rs, float scale) {
  float xs = xv * rs;
  float q  = copysignf(snap(fabsf(xs)), xs);
  return f2bf(q * scale);
}

// One 16-lane cluster per 128-elem group; 4 groups per wave, 16 per block.
__global__ __launch_bounds__(256) void quant_kernel(const float* __restrict__ x,
                                                    unsigned short* __restrict__ dq) {
  const int wid = (blockIdx.x << 2) + (threadIdx.x >> 6);
  const int l   = threadIdx.x & 63;
  const int sub = l >> 4, t = l & 15;
  const size_t base = ((size_t)wid * 4 + sub) * 128;
  const float4* px = reinterpret_cast<const float4*>(x + base);
  float4 v0 = px[t];
  float4 v1 = px[16 + t];
  float amax = fmaxf(fmaxf(fmaxf(fabsf(v0.x), fabsf(v0.y)), fmaxf(fabsf(v0.z), fabsf(v0.w))),
                     fmaxf(fmaxf(fabsf(v1.x), fabsf(v1.y)), fmaxf(fabsf(v1.z), fabsf(v1.w))));
  #pragma unroll
  for (int m = 1; m < 16; m <<= 1) amax = fmaxf(amax, __shfl_xor(amax, m, 64));
  float scale = amax / 6.0f;
  if (scale == 0.0f) scale = 1.0f;
  const float rs = 1.0f / scale;
  ushort4 o0, o1;
  o0.x = qdq(v0.x, rs, scale); o0.y = qdq(v0.y, rs, scale);
  o0.z = qdq(v0.z, rs, scale); o0.w = qdq(v0.w, rs, scale);
  o1.x = qdq(v1.x, rs, scale); o1.y = qdq(v1.y, rs, scale);
  o1.z = qdq(v1.z, rs, scale); o1.w = qdq(v1.w, rs, scale);
  reinterpret_cast<ushort4*>(dq + base)[t]      = o0;
  reinterpret_cast<ushort4*>(dq + base)[16 + t] = o1;
}

__global__ __launch_bounds__(256) void wconv_kernel(const float* __restrict__ w,
                                                    unsigned short* __restrict__ o) {
  const int n4 = (N_DIM * K_DIM) / 4;
  for (int i = blockIdx.x * 256 + threadIdx.x; i < n4; i += gridDim.x * 256) {
    float4 v = reinterpret_cast<const float4*>(w)[i];
    ushort4 u;
    u.x = f2bf(v.x); u.y = f2bf(v.y); u.z = f2bf(v.z); u.w = f2bf(v.w);
    reinterpret_cast<ushort4*>(o)[i] = u;
  }
}

__device__ __forceinline__ bf16x8 lds_ld(const ushort_t* p) {
  return *reinterpret_cast<const bf16x8*>(p);
}

// Stage one 16KB half-tile (128 rows x 64 cols bf16): 2 x 16B per thread.
// Dest is a STATIC __shared__ array (compile-time identity) so the waitcnt
// pass can alias-disambiguate ds_reads against outstanding LDS-DMA instead of
// inserting a conservative drain before every phase's reads (the R2-R4 flat-
// line). LDS dest linear; swizzle pre-applied on the global source (T21).
__device__ __forceinline__ void stg(const ushort_t* g0, const ushort_t* g1,
                                    ushort_t (&slot)[8192], int wid) {
  __builtin_amdgcn_global_load_lds((const __attribute__((address_space(1))) void*)g0,
      (__attribute__((address_space(3))) void*)(&slot[wid * 512]), 16, 0, 0);
  __builtin_amdgcn_global_load_lds((const __attribute__((address_space(1))) void*)g1,
      (__attribute__((address_space(3))) void*)(&slot[4096 + wid * 512]), 16, 0, 0);
}

// One K-tile (BK=64): 4 phases {ds_reads -> stage 1 half-tile -> barrier ->
// 16 MFMA (setprio) -> barrier}; counted vmcnt(4) only at phase 4. All LDS
// slots are static array refs; parity is resolved at the call site.
template<bool S12, bool S34, int VM>
__device__ __forceinline__ void tile_iter(
    int t,
    ushort_t (&rA)[8192],  ushort_t (&rB)[8192],   // read slots (this tile)
    ushort_t (&dB1)[8192], ushort_t (&dA1)[8192],  // dest half1, parity 1-P (t+1)
    ushort_t (&dB0)[8192], ushort_t (&dA0)[8192],  // dest half0, parity P   (t+2)
    int wid, const int (&roA)[8], const int (&roB)[4], int swz0, int swz1,
    const ushort_t* pa0, const ushort_t* pa1,
    const ushort_t* pb0, const ushort_t* pb1,
    f32x4 (&acc)[8][4]) {
  bf16x8 a0[4], a1[4], b0[4], b1[4];

  // ---- phase 1: read A(m0-3) + B(n0-1); stage B-half1(t+1); MFMA m0-3 x n0-1
  #pragma unroll
  for (int i = 0; i < 4; ++i) {
    a0[i] = lds_ld(&rA[roA[i] + swz0]);
    a1[i] = lds_ld(&rA[roA[i] + swz1]);
  }
  #pragma unroll
  for (int n = 0; n < 2; ++n) {
    b0[n] = lds_ld(&rB[roB[n] + swz0]);
    b1[n] = lds_ld(&rB[roB[n] + swz1]);
  }
  if constexpr (S12)
    stg(pb0 + (size_t)128 * K_DIM + (size_t)(t + 1) * 64,
        pb1 + (size_t)128 * K_DIM + (size_t)(t + 1) * 64, dB1, wid);
  BARR();
  __builtin_amdgcn_s_setprio(1);
  #pragma unroll
  for (int i = 0; i < 4; ++i)
    #pragma unroll
    for (int n = 0; n < 2; ++n) {
      acc[i][n] = __builtin_amdgcn_mfma_f32_16x16x32_bf16(a0[i], b0[n], acc[i][n], 0, 0, 0);
      acc[i][n] = __builtin_amdgcn_mfma_f32_16x16x32_bf16(a1[i], b1[n], acc[i][n], 0, 0, 0);
    }
  __builtin_amdgcn_s_setprio(0);
  BARR();

  // ---- phase 2: read B(n2-3); stage A-half1(t+1); MFMA m0-3 x n2-3
  #pragma unroll
  for (int n = 2; n < 4; ++n) {
    b0[n] = lds_ld(&rB[roB[n] + swz0]);
    b1[n] = lds_ld(&rB[roB[n] + swz1]);
  }
  if constexpr (S12)
    stg(pa0 + (size_t)128 * K_DIM + (size_t)(t + 1) * 64,
        pa1 + (size_t)128 * K_DIM + (size_t)(t + 1) * 64, dA1, wid);
  BARR();
  __builtin_amdgcn_s_setprio(1);
  #pragma unroll
  for (int i = 0; i < 4; ++i)
    #pragma unroll
    for (int n = 2; n < 4; ++n) {
      acc[i][n] = __builtin_amdgcn_mfma_f32_16x16x32_bf16(a0[i], b0[n], acc[i][n], 0, 0, 0);
      acc[i][n] = __builtin_amdgcn_mfma_f32_16x16x32_bf16(a1[i], b1[n], acc[i][n], 0, 0, 0);
    }
  __builtin_amdgcn_s_setprio(0);
  BARR();

  // ---- phase 3: read A(m4-7); stage B-half0(t+2); MFMA m4-7 x n2-3
  #pragma unroll
  for (int i = 0; i < 4; ++i) {
    a0[i] = lds_ld(&rA[roA[4 + i] + swz0]);
    a1[i] = lds_ld(&rA[roA[4 + i] + swz1]);
  }
  if constexpr (S34)
    stg(pb0 + (size_t)(t + 2) * 64, pb1 + (size_t)(t + 2) * 64, dB0, wid);
  BARR();
  __builtin_amdgcn_s_setprio(1);
  #pragma unroll
  for (int i = 0; i < 4; ++i)
    #pragma unroll
    for (int n = 2; n < 4; ++n) {
      acc[4 + i][n] = __builtin_amdgcn_mfma_f32_16x16x32_bf16(a0[i], b0[n], acc[4 + i][n], 0, 0, 0);
      acc[4 + i][n] = __builtin_amdgcn_mfma_f32_16x16x32_bf16(a1[i], b1[n], acc[4 + i][n], 0, 0, 0);
    }
  __builtin_amdgcn_s_setprio(0);
  BARR();

  // ---- phase 4: stage A-half0(t+2); MFMA m4-7 x n0-1; counted vmcnt; barrier
  if constexpr (S34)
    stg(pa0 + (size_t)(t + 2) * 64, pa1 + (size_t)(t + 2) * 64, dA0, wid);
  BARR();
  __builtin_amdgcn_s_setprio(1);
  #pragma unroll
  for (int i = 0; i < 4; ++i)
    #pragma unroll
    for (int n = 0; n < 2; ++n) {
      acc[4 + i][n] = __builtin_amdgcn_mfma_f32_16x16x32_bf16(a0[i], b0[n], acc[4 + i][n], 0, 0, 0);
      acc[4 + i][n] = __builtin_amdgcn_mfma_f32_16x16x32_bf16(a1[i], b1[n], acc[4 + i][n], 0, 0, 0);
    }
  __builtin_amdgcn_s_setprio(0);
  if constexpr (VM == 4) {
    asm volatile("s_waitcnt vmcnt(4)");
    __builtin_amdgcn_sched_barrier(0);   // rule #18: pin later ds_reads below the wait
  } else if constexpr (VM == 0) {
    asm volatile("s_waitcnt vmcnt(0)");
    __builtin_amdgcn_sched_barrier(0);
  }
  BARR();
}

// K-loop with compile-time wave-half selection (WM: A half, WH: B half).
template<int WM, int WH>
__device__ __forceinline__ void krun(
    ushort_t (&sA0p0)[8192], ushort_t (&sA0p1)[8192],
    ushort_t (&sA1p0)[8192], ushort_t (&sA1p1)[8192],
    ushort_t (&sB0p0)[8192], ushort_t (&sB0p1)[8192],
    ushort_t (&sB1p0)[8192], ushort_t (&sB1p1)[8192],
    int wid, const int (&roA)[8], const int (&roB)[4], int swz0, int swz1,
    const ushort_t* pa0, const ushort_t* pa1,
    const ushort_t* pb0, const ushort_t* pb1,
    f32x4 (&acc)[8][4]) {
  ushort_t (&rAp0)[8192] = WM ? sA1p0 : sA0p0;
  ushort_t (&rAp1)[8192] = WM ? sA1p1 : sA0p1;
  ushort_t (&rBp0)[8192] = WH ? sB1p0 : sB0p0;
  ushort_t (&rBp1)[8192] = WH ? sB1p1 : sB0p1;

  // Prologue: tile0 all four slots + tile1 half0; last 2 half-tiles in flight.
  stg(pb0, pb1, sB0p0, wid);                                            // B0(0)
  stg(pa0, pa1, sA0p0, wid);                                            // A0(0)
  stg(pb0 + (size_t)128 * K_DIM, pb1 + (size_t)128 * K_DIM, sB1p0, wid); // B1(0)
  stg(pa0 + (size_t)128 * K_DIM, pa1 + (size_t)128 * K_DIM, sA1p0, wid); // A1(0)
  stg(pb0 + 64, pb1 + 64, sB0p1, wid);                                  // B0(1)
  stg(pa0 + 64, pa1 + 64, sA0p1, wid);                                  // A0(1)
  asm volatile("s_waitcnt vmcnt(4)");
  __builtin_amdgcn_sched_barrier(0);
  BARR();

  for (int t = 0; t < 62; t += 2) {   // tiles 0..61, static parity
    tile_iter<true, true, 4>(t,     rAp0, rBp0, sB1p1, sA1p1, sB0p0, sA0p0,
                             wid, roA, roB, swz0, swz1, pa0, pa1, pb0, pb1, acc);
    tile_iter<true, true, 4>(t + 1, rAp1, rBp1, sB1p0, sA1p0, sB0p1, sA0p1,
                             wid, roA, roB, swz0, swz1, pa0, pa1, pb0, pb1, acc);
  }
  tile_iter<true, false, 0>(62, rAp0, rBp0, sB1p1, sA1p1, sB0p0, sA0p0,
                            wid, roA, roB, swz0, swz1, pa0, pa1, pb0, pb1, acc);
  tile_iter<false, false, -1>(63, rAp1, rBp1, sB1p0, sA1p0, sB0p1, sA0p1,
                              wid, roA, roB, swz0, swz1, pa0, pa1, pb0, pb1, acc);
}

// 256x256 tile, BK=64, 8 waves (2M x 4N), 8-phase/2-tile static-slot schedule,
// XOR swizzle, counted vmcnt. A = deq [M,K], B = W [N,K] (both row-major bf16).
__global__ __launch_bounds__(512, 2) void gemm256(const ushort_t* __restrict__ A,
                                                  const ushort_t* __restrict__ B,
                                                  const float* __restrict__ bias,
                                                  float* __restrict__ C) {
  __shared__ ushort_t sA0p0[8192], sA0p1[8192], sA1p0[8192], sA1p1[8192];
  __shared__ ushort_t sB0p0[8192], sB0p1[8192], sB1p0[8192], sB1p1[8192];
  const int tid  = threadIdx.x;
  const int wid  = tid >> 6, lane = tid & 63;
  const int r    = lane & 15, h = lane >> 4;
  const int wm   = wid >> 2, wn = wid & 3;
  const int bn   = blockIdx.x, bm = blockIdx.y;

  // ds_read swizzle: col16-slice = (kk*4+h) ^ (row&7); row&7 == lane&7.
  const int x7   = lane & 7;
  const int swz0 = ((h) ^ x7) << 3;         // ushort offset, kk=0
  const int swz1 = ((4 | h) ^ x7) << 3;     // kk=1
  int roA[8], roB[4];
  #pragma unroll
  for (int m = 0; m < 8; ++m) roA[m] = (m * 16 + r) * 64;
  #pragma unroll
  for (int n = 0; n < 4; ++n) roB[n] = ((wn & 1) * 64 + n * 16 + r) * 64;

  // staging source: LDS row = tid>>3, 16B-slice q = tid&7,
  // global slice = q ^ (row&7) (inverse of the read-side XOR).
  const int srow0 = tid >> 3;
  const int cst   = ((tid & 7) ^ (srow0 & 7)) << 3;
  const ushort_t* pa0 = A + (size_t)(bm * 256 + srow0) * K_DIM + cst;
  const ushort_t* pa1 = A + (size_t)(bm * 256 + 64 + srow0) * K_DIM + cst;
  const ushort_t* pb0 = B + (size_t)(bn * 256 + srow0) * K_DIM + cst;
  const ushort_t* pb1 = B + (size_t)(bn * 256 + 64 + srow0) * K_DIM + cst;

  f32x4 acc[8][4];
  #pragma unroll
  for (int m = 0; m < 8; ++m)
    #pragma unroll
    for (int n = 0; n < 4; ++n) acc[m][n] = (f32x4){0.f, 0.f, 0.f, 0.f};

  const int wh = wn >> 1;
  if (wm == 0) {
    if (wh == 0) krun<0, 0>(sA0p0, sA0p1, sA1p0, sA1p1, sB0p0, sB0p1, sB1p0, sB1p1,
                            wid, roA, roB, swz0, swz1, pa0, pa1, pb0, pb1, acc);
    else         krun<0, 1>(sA0p0, sA0p1, sA1p0, sA1p1, sB0p0, sB0p1, sB1p0, sB1p1,
                            wid, roA, roB, swz0, swz1, pa0, pa1, pb0, pb1, acc);
  } else {
    if (wh == 0) krun<1, 0>(sA0p0, sA0p1, sA1p0, sA1p1, sB0p0, sB0p1, sB1p0, sB1p1,
                            wid, roA, roB, swz0, swz1, pa0, pa1, pb0, pb1, acc);
    else         krun<1, 1>(sA0p0, sA0p1, sA1p0, sA1p1, sB0p0, sB0p1, sB1p0, sB1p1,
                            wid, roA, roB, swz0, swz1, pa0, pa1, pb0, pb1, acc);
  }

  // Epilogue: C/D layout col=lane&15, row=(lane>>4)*4+reg  [m89/m91]
  const int orow = bm * 256 + wm * 128;
  const int ocol = bn * 256 + wn * 64;
  #pragma unroll
  for (int n = 0; n < 4; ++n) {
    const int col = ocol + n * 16 + r;
    const float bv = bias[col];
    #pragma unroll
    for (int m = 0; m < 8; ++m) {
      const int rb = orow + m * 16 + h * 4;
      #pragma unroll
      for (int j = 0; j < 4; ++j)
        C[(size_t)(rb + j) * N_DIM + col] = acc[m][n][j] + bv;
    }
  }
}

// Emergency fallback if ws is too small: fused fp32, slow but correct.
__global__ __launch_bounds__(256) void fused_naive(const float* __restrict__ x,
                                                   const float* __restrict__ w,
                                                   const float* __restrict__ bias,
                                                   float* __restrict__ out) {
  __shared__ float xq[K_DIM];
  const int row = blockIdx.x;
  const float* xr = x + (size_t)row * K_DIM;
  const int t = threadIdx.x;
  const int g = t >> 3, s = t & 7;
  float vals[16];
  float amax = 0.f;
  #pragma unroll
  for (int i = 0; i < 16; ++i) {
    vals[i] = xr[g * 128 + s * 16 + i];
    amax = fmaxf(amax, fabsf(vals[i]));
  }
  #pragma unroll
  for (int m = 1; m < 8; m <<= 1) amax = fmaxf(amax, __shfl_xor(amax, m, 64));
  float scale = amax / 6.0f;
  if (scale == 0.f) scale = 1.f;
  const float rs = 1.0f / scale;
  #pragma unroll
  for (int i = 0; i < 16; ++i) {
    float xs = vals[i] * rs;
    xq[g * 128 + s * 16 + i] = copysignf(snap(fabsf(xs)), xs) * scale;
  }
  __syncthreads();
  #pragma unroll
  for (int i = 0; i < 4; ++i) {
    const int o = i * 256 + t;
    const float* wrow = w + (size_t)o * K_DIM;
    float acc = 0.f;
    for (int k = 0; k < K_DIM; k += 4) {
      float4 wv = *reinterpret_cast<const float4*>(wrow + k);
      acc += xq[k] * wv.x + xq[k + 1] * wv.y + xq[k + 2] * wv.z + xq[k + 3] * wv.w;
    }
    out[(size_t)row * N_DIM + o] = acc + bias[o];
  }
}

extern "C" void kernel_launch(void* const* d_in, const int* in_sizes, int n_in,
                              void* d_out, int out_size, void* d_ws, size_t ws_size,
                              hipStream_t stream) {
  const float* x    = (const float*)d_in[0];
  const float* wgt  = (const float*)d_in[1];
  const float* bias = (const float*)d_in[2];
  float* out = (float*)d_out;

  const size_t deq_bytes = (size_t)M_DIM * K_DIM * 2;
  const size_t wb_bytes  = (size_t)N_DIM * K_DIM * 2;
  if (ws_size >= deq_bytes + wb_bytes) {
    ushort_t* deq = (ushort_t*)d_ws;
    ushort_t* wb  = (ushort_t*)((char*)d_ws + deq_bytes);
    quant_kernel<<<(M_DIM * (K_DIM / 128)) / 16, 256, 0, stream>>>(x, deq);
    wconv_kernel<<<1024, 256, 0, stream>>>(wgt, wb);
    gemm256<<<dim3(N_DIM / 256, M_DIM / 256), 512, 0, stream>>>(deq, wb, bias, out);
  } else {
    fused_naive<<<M_DIM, 256, 0, stream>>>(x, wgt, bias, out);
  }
}